// Round 1
// 216.662 us; speedup vs baseline: 1.0249x; 1.0249x over previous
//
#include <hip/hip_runtime.h>
#include <cstddef>

// Problem constants (from reference)
#define QN 10000
#define DD 64
#define MM 50
#define BB 64
#define TT 512
#define WPAD 52   // padded w row stride in floats (208 B -> 16B-aligned rows)
#define MG 25     // m's per wave in the 2-way m-split scan kernels

// ---------------------------------------------------------------------------
// k1a: w = softmax(k @ Mk^T). One wave per row; Mk row in VGPRs (64 regs).
// ---------------------------------------------------------------------------
__global__ __launch_bounds__(256) void k1a_w(
    const int* __restrict__ question, const float* __restrict__ k_emb,
    const float* __restrict__ Mk, float* __restrict__ w_buf) {
  const int lane = threadIdx.x & 63;
  const int wslot = __builtin_amdgcn_readfirstlane((int)(threadIdx.x >> 6));
  const int wid = blockIdx.x * 4 + wslot;

  float mk[64];
  const int mrow = lane < MM ? lane : (MM - 1);
#pragma unroll
  for (int i = 0; i < 64; i += 4) {
    const float4 t4 = *(const float4*)(Mk + mrow * 64 + i);
    mk[i] = t4.x; mk[i + 1] = t4.y; mk[i + 2] = t4.z; mk[i + 3] = t4.w;
  }

  for (int row = wid; row < BB * TT; row += 4096) {
    const int q = question[row];                       // wave-uniform
    const float* __restrict__ krow = k_emb + (size_t)q * 64;
    float l0 = 0.f, l1 = 0.f, l2 = 0.f, l3 = 0.f;
#pragma unroll
    for (int i = 0; i < 64; i += 4) {
      const float4 kv = *(const float4*)(krow + i);    // uniform -> s_load_dwordx4
      l0 = fmaf(kv.x, mk[i], l0);
      l1 = fmaf(kv.y, mk[i + 1], l1);
      l2 = fmaf(kv.z, mk[i + 2], l2);
      l3 = fmaf(kv.w, mk[i + 3], l3);
    }
    const float lm = (l0 + l1) + (l2 + l3);
    float lv = (lane < MM) ? lm : -3.4e38f;
#pragma unroll
    for (int off = 32; off > 0; off >>= 1) lv = fmaxf(lv, __shfl_xor(lv, off));
    float pe = (lane < MM) ? __expf(lm - lv) : 0.f;
    float ss = pe;
#pragma unroll
    for (int off = 32; off > 0; off >>= 1) ss += __shfl_xor(ss, off);
    if (lane < MM) w_buf[(size_t)row * WPAD + lane] = pe / ss;
  }
}

// ---------------------------------------------------------------------------
// k1b: e = sigmoid(v@e_W+e_b), a = tanh(v@a_W+a_b), both pre-multiplied by
// (mask==1). Interleaved store {e,a} per (row,d) so the scan kernels do one
// dwordx2 load per step. Mask folding makes the scan update branchless:
// mask!=1 -> e=a=0 -> alpha=1, beta=0 -> identity step.
// ---------------------------------------------------------------------------
__global__ __launch_bounds__(256) void k1b_ea(
    const int* __restrict__ question, const int* __restrict__ response,
    const float* __restrict__ mask, const float* __restrict__ v_emb,
    const float* __restrict__ e_W, const float* __restrict__ e_b,
    const float* __restrict__ a_W, const float* __restrict__ a_b,
    float* __restrict__ ea_buf) {
  const int lane = threadIdx.x & 63;
  const int wslot = __builtin_amdgcn_readfirstlane((int)(threadIdx.x >> 6));
  const int wid = blockIdx.x * 4 + wslot;

  float ew[64], aw[64];
#pragma unroll
  for (int i = 0; i < 64; ++i) {
    ew[i] = e_W[i * 64 + lane];
    aw[i] = a_W[i * 64 + lane];
  }
  const float eb = e_b[lane];
  const float ab = a_b[lane];

  for (int row = wid; row < BB * TT; row += 4096) {
    const int q = question[row];
    const int r = response[row];
    const float mf = (mask[row] == 1.0f) ? 1.0f : 0.0f; // wave-uniform
    const float* __restrict__ vrow = v_emb + ((size_t)q + (size_t)QN * r) * 64;
    float e0 = eb, e1 = 0.f, a0 = ab, a1 = 0.f;
#pragma unroll
    for (int i = 0; i < 64; i += 2) {
      const float2 vv = *(const float2*)(vrow + i);    // uniform -> s_load
      e0 = fmaf(vv.x, ew[i], e0);
      a0 = fmaf(vv.x, aw[i], a0);
      e1 = fmaf(vv.y, ew[i + 1], e1);
      a1 = fmaf(vv.y, aw[i + 1], a1);
    }
    const float se = e0 + e1, sa = a0 + a1;
    const float ev = 1.f / (1.f + __expf(-se));
    const float t2 = __expf(2.f * sa);
    const float av = 1.f - 2.f / (t2 + 1.f);           // tanh
    float2 o; o.x = ev * mf; o.y = av * mf;
    *(float2*)(ea_buf + (size_t)row * 128 + lane * 2) = o;
  }
}

// ---------------------------------------------------------------------------
// kA: per-(b,chunk,mgroup) composed affine transform per (m,d).
// One wave per unit2 = (b*C+c)*2+g; lane = d; 25 m's in registers (2-way
// m-split doubles wave count and halves VGPR arrays). Branchless inner loop
// (mask folded into e/a) lets the compiler pipeline loads across steps.
//   AB layout: [b][c][mrow][d][{A,B}]  (float2 per (m,d))
// ---------------------------------------------------------------------------
__global__ __launch_bounds__(256) void kA_chunk(
    const float* __restrict__ w_buf, const float* __restrict__ ea_buf,
    float* __restrict__ AB, int logC, int L) {
  const int lane = threadIdx.x & 63;
  const int wslot = __builtin_amdgcn_readfirstlane((int)(threadIdx.x >> 6));
  const int u2 = blockIdx.x * 4 + wslot;
  const int C = 1 << logC;
  if (u2 >= BB * C * 2) return;
  const int g = u2 & 1;
  const int unit = u2 >> 1;                            // b*C + c
  const int b = unit >> logC;
  const int c = unit & (C - 1);

  float Am[MG], Bm[MG];
#pragma unroll
  for (int m = 0; m < MG; ++m) { Am[m] = 1.f; Bm[m] = 0.f; }

  const size_t rowbase = (size_t)b * TT + c * L;
#pragma unroll 2
  for (int j = 0; j < L; ++j) {
    const size_t row = rowbase + j;
    const float2 ea = *(const float2*)(ea_buf + row * 128 + lane * 2);
    const float* __restrict__ wr = w_buf + row * WPAD + g * MG; // uniform
#pragma unroll
    for (int m = 0; m < MG; ++m) {
      const float wm = wr[m];
      const float al = fmaf(-wm, ea.x, 1.0f);
      const float be = wm * ea.y;
      Am[m] *= al;
      Bm[m] = fmaf(Bm[m], al, be);
    }
  }
  float* __restrict__ abp = AB + (size_t)unit * 6400 + (g * MG) * 128 + lane * 2;
#pragma unroll
  for (int m = 0; m < MG; ++m) {
    float2 o; o.x = Am[m]; o.y = Bm[m];
    *(float2*)(abp + m * 128) = o;
  }
}

// ---------------------------------------------------------------------------
// kB: sequential over C chunks, parallel over B*M*D = 204,800 elements.
// C==32 path loads ALL chunk coefficients up front (32 independent float2
// loads -> one latency exposure instead of 32 serialized ones).
// ---------------------------------------------------------------------------
__global__ __launch_bounds__(256) void kB_entry(
    const float* __restrict__ AB, const float* __restrict__ Mv0,
    float* __restrict__ entry, int C) {
  const int idx = blockIdx.x * 256 + (int)threadIdx.x; // < B*3200
  const int b = idx / (MM * 64);
  const int r = idx - b * (MM * 64);                   // m*64 + d
  float s = Mv0[r];
  const float* __restrict__ abp = AB + (size_t)b * C * 6400 + (size_t)r * 2;
  float* __restrict__ ep = entry + (size_t)b * C * 3200 + r;
  if (C == 32) {
    float2 ab[32];
#pragma unroll
    for (int c = 0; c < 32; ++c)
      ab[c] = *(const float2*)(abp + (size_t)c * 6400);
#pragma unroll
    for (int c = 0; c < 32; ++c) {
      ep[(size_t)c * 3200] = s;
      s = fmaf(ab[c].x, s, ab[c].y);
    }
  } else {
    float2 cur = *(const float2*)(abp);
    for (int c = 0; c < C; ++c) {
      ep[(size_t)c * 3200] = s;
      float2 nxt; nxt.x = 1.f; nxt.y = 0.f;
      if (c + 1 < C) nxt = *(const float2*)(abp + (size_t)(c + 1) * 6400);
      s = fmaf(cur.x, s, cur.y);
      cur = nxt;
    }
  }
}

// ---------------------------------------------------------------------------
// kC: replay each chunk from its entry state, emitting partial reads.
// One wave per (b,c,mgroup); lane = d; s[25] in registers; w in SGPRs.
// Partial read sums (over this wave's 25 m's) go to read2[g]; k3 adds the
// two halves -- no cross-wave sync needed. Branchless steady-state loop.
// ---------------------------------------------------------------------------
__global__ __launch_bounds__(256) void kC_read(
    const float* __restrict__ w_buf, const float* __restrict__ ea_buf,
    const float* __restrict__ entry, const float* __restrict__ Mv0,
    float* __restrict__ read2, int logC, int L, int use_mv0) {
  const int lane = threadIdx.x & 63;
  const int wslot = __builtin_amdgcn_readfirstlane((int)(threadIdx.x >> 6));
  const int u2 = blockIdx.x * 4 + wslot;
  const int C = 1 << logC;
  if (u2 >= BB * C * 2) return;
  const int g = u2 & 1;
  const int unit = u2 >> 1;                            // b*C + c
  const int b = unit >> logC;
  const int c = unit & (C - 1);

  float s[MG];
  if (use_mv0) {
#pragma unroll
    for (int m = 0; m < MG; ++m) s[m] = Mv0[(g * MG + m) * 64 + lane];
  } else {
    const float* __restrict__ ep =
        entry + (size_t)unit * 3200 + (g * MG) * 64 + lane;
#pragma unroll
    for (int m = 0; m < MG; ++m) s[m] = ep[m * 64];
  }

  const int t0 = c * L;
  float* __restrict__ rb = read2 + (size_t)g * ((size_t)BB * (TT - 1) * 64);
  int j0 = 0;
  if (t0 == 0) {
    // step t=0: update only, no read emitted
    const size_t row = (size_t)b * TT;
    const float2 ea = *(const float2*)(ea_buf + row * 128 + lane * 2);
    const float* __restrict__ wr = w_buf + row * WPAD + g * MG;
#pragma unroll
    for (int m = 0; m < MG; ++m)
      s[m] = fmaf(wr[m], fmaf(-s[m], ea.x, ea.y), s[m]);
    j0 = 1;
  }
#pragma unroll 2
  for (int j = j0; j < L; ++j) {
    const int t = t0 + j;
    const size_t row = (size_t)b * TT + t;
    const float2 ea = *(const float2*)(ea_buf + row * 128 + lane * 2);
    const float* __restrict__ wr = w_buf + row * WPAD + g * MG; // uniform

    float a0 = 0.f, a1 = 0.f;
#pragma unroll
    for (int m = 0; m < MG - 1; m += 2) {
      a0 = fmaf(wr[m], s[m], a0);
      a1 = fmaf(wr[m + 1], s[m + 1], a1);
    }
    a0 = fmaf(wr[MG - 1], s[MG - 1], a0);              // MG=25 is odd
    rb[((size_t)b * (TT - 1) + (t - 1)) * 64 + lane] = a0 + a1;

#pragma unroll
    for (int m = 0; m < MG; ++m)
      s[m] = fmaf(wr[m], fmaf(-s[m], ea.x, ea.y), s[m]);
  }
}

// ---------------------------------------------------------------------------
// k3: f = tanh([read | k_{t+1}] @ f_W + f_b); p = f @ p_W + p_b
// read = read2[part0] + read2[part1] (summed here for free).
// ---------------------------------------------------------------------------
__global__ __launch_bounds__(256) void k3_out(
    const int* __restrict__ question, const float* __restrict__ k_emb,
    const float* __restrict__ read2,
    const float* __restrict__ f_W, const float* __restrict__ f_b,
    const float* __restrict__ p_W, const float* __restrict__ p_b,
    float* __restrict__ out) {
  const int lane = threadIdx.x & 63;
  const int wslot = __builtin_amdgcn_readfirstlane((int)(threadIdx.x >> 6));
  const int wid = blockIdx.x * 4 + wslot;
  const size_t RN = (size_t)BB * (TT - 1) * 64;

  float fw[128];
#pragma unroll
  for (int i = 0; i < 128; ++i) fw[i] = f_W[i * 64 + lane];
  const float fb = f_b[lane];
  const float pw = p_W[lane];
  const float pb = p_b[0];

  for (int row = wid; row < BB * (TT - 1); row += 4096) {
    const int b = row / (TT - 1);
    const int tp = row - b * (TT - 1);
    const float* __restrict__ r0 = read2 + (size_t)row * 64;
    const float* __restrict__ r1 = r0 + RN;
    const int qn = question[b * TT + tp + 1];          // wave-uniform
    const float* __restrict__ krow = k_emb + (size_t)qn * 64;

    float f0 = fb, f1 = 0.f, f2 = 0.f, f3 = 0.f;
#pragma unroll
    for (int i = 0; i < 64; i += 4) {
      const float4 x0 = *(const float4*)(r0 + i);
      const float4 x1 = *(const float4*)(r1 + i);
      f0 = fmaf(x0.x + x1.x, fw[i], f0);
      f1 = fmaf(x0.y + x1.y, fw[i + 1], f1);
      f2 = fmaf(x0.z + x1.z, fw[i + 2], f2);
      f3 = fmaf(x0.w + x1.w, fw[i + 3], f3);
    }
#pragma unroll
    for (int i = 0; i < 64; i += 4) {
      const float4 kv = *(const float4*)(krow + i);
      f0 = fmaf(kv.x, fw[64 + i], f0);
      f1 = fmaf(kv.y, fw[64 + i + 1], f1);
      f2 = fmaf(kv.z, fw[64 + i + 2], f2);
      f3 = fmaf(kv.w, fw[64 + i + 3], f3);
    }
    const float f = (f0 + f1) + (f2 + f3);
    const float t2 = __expf(2.f * f);
    const float fv = 1.f - 2.f / (t2 + 1.f);           // tanh

    float acc = fv * pw;
#pragma unroll
    for (int off = 32; off > 0; off >>= 1) acc += __shfl_xor(acc, off);
    if (lane == 0) out[row] = acc + pb;
  }
}

// ---------------------------------------------------------------------------
extern "C" void kernel_launch(void* const* d_in, const int* in_sizes, int n_in,
                              void* d_out, int out_size, void* d_ws, size_t ws_size,
                              hipStream_t stream) {
  const int*   question = (const int*)d_in[0];
  const int*   response = (const int*)d_in[1];
  const float* mask     = (const float*)d_in[2];
  const float* k_emb    = (const float*)d_in[3];
  const float* v_emb    = (const float*)d_in[4];
  const float* Mk       = (const float*)d_in[5];
  const float* Mv0      = (const float*)d_in[6];
  const float* e_W      = (const float*)d_in[7];
  const float* e_b      = (const float*)d_in[8];
  const float* a_W      = (const float*)d_in[9];
  const float* a_b      = (const float*)d_in[10];
  const float* f_W      = (const float*)d_in[11];
  const float* f_b      = (const float*)d_in[12];
  const float* p_W      = (const float*)d_in[13];
  const float* p_b      = (const float*)d_in[14];
  float* out = (float*)d_out;

  // workspace layout (floats)
  const size_t wN  = (size_t)BB * TT * WPAD;       // 1,703,936
  const size_t eaN = (size_t)BB * TT * 128;        // 4,194,304 (interleaved e,a)
  const size_t r2N = 2ull * BB * (TT - 1) * 64;    // 4,186,112 (2 read partials)
  float* ws = (float*)d_ws;
  float* w_buf    = ws;
  float* ea_buf   = w_buf + wN;
  float* read2    = ea_buf + eaN;
  float* AB_arr   = read2 + r2N;
  const size_t baseN = wN + eaN + r2N;             // 10,084,352 floats

  // choose the largest chunk count C that fits the workspace
  // per-C cost: AB (2*3200*B*C) + entry (3200*B*C) = 9600*B*C floats
  int C = 32, logC = 5;
  while (C >= 2) {
    const size_t need = (baseN + 9600ull * BB * C) * sizeof(float);
    if (need <= ws_size) break;
    C >>= 1; logC -= 1;
  }
  const int useChunks = (C >= 2);
  if (!useChunks) { C = 1; logC = 0; }
  const int L = TT / C;
  float* entry = AB_arr + 6400ull * BB * C;

  hipLaunchKernelGGL(k1a_w, dim3(1024), dim3(256), 0, stream,
                     question, k_emb, Mk, w_buf);
  hipLaunchKernelGGL(k1b_ea, dim3(1024), dim3(256), 0, stream,
                     question, response, mask, v_emb, e_W, e_b, a_W, a_b, ea_buf);

  const int units2 = BB * C * 2;
  const int ublocks = (units2 + 3) / 4;
  if (useChunks) {
    hipLaunchKernelGGL(kA_chunk, dim3(ublocks), dim3(256), 0, stream,
                       w_buf, ea_buf, AB_arr, logC, L);
    hipLaunchKernelGGL(kB_entry, dim3((BB * MM * 64) / 256), dim3(256), 0, stream,
                       AB_arr, Mv0, entry, C);
  }
  hipLaunchKernelGGL(kC_read, dim3(ublocks), dim3(256), 0, stream,
                     w_buf, ea_buf, entry, Mv0, read2,
                     logC, L, useChunks ? 0 : 1);

  hipLaunchKernelGGL(k3_out, dim3(1024), dim3(256), 0, stream,
                     question, k_emb, read2, f_W, f_b, p_W, p_b, out);
}